// Round 1
// baseline (888.551 us; speedup 1.0000x reference)
//
#include <hip/hip_runtime.h>
#include <math.h>

#define Hdim 4096
#define NE 256

// ---------------------------------------------------------------------------
// Phase 1: logits[T,256] = X[T,4096] @ W[256,4096]^T   (fp32, vector ALU)
// Block: 512 threads (8 waves). Tile: BM=32 tokens x all 256 experts, BK=32.
// LDS stride 36 floats: keeps float4 16B alignment AND b128 conflict-free
// (bank start = (4*lane + k) % 32 -> exactly 8 accesses/bank = b128 minimum).
// Register-prefetch pipeline: load chunk k+1 to regs while computing chunk k.
// ---------------------------------------------------------------------------
__global__ __launch_bounds__(512, 2)
void moe_gate_gemm(const float* __restrict__ X, const float* __restrict__ W,
                   float* __restrict__ logits) {
  __shared__ float xs[32 * 36];
  __shared__ float wsh[256 * 36];
  const int tid = threadIdx.x;
  const int eg = tid & 63;   // expert lane 0..63
  const int tg = tid >> 6;   // wave id 0..7 -> token group
  const long bm0 = (long)blockIdx.x * 32;

  float acc[4][4];
#pragma unroll
  for (int i = 0; i < 4; ++i)
#pragma unroll
    for (int j = 0; j < 4; ++j) acc[i][j] = 0.f;

  // X staging: first 256 threads load one float4: row = tid/8, k0 = (tid%8)*4
  const int xt = tid >> 3;
  const int xk = (tid & 7) << 2;
  const float* xsrc = X + (bm0 + (long)xt) * Hdim + xk;

  // W staging: 4 float4 per thread: flat4 = l*512+tid -> e = flat4/8, k0 = (flat4%8)*4
  int we[4], wk[4];
  const float* wsrc[4];
#pragma unroll
  for (int l = 0; l < 4; ++l) {
    const int f4 = l * 512 + tid;
    we[l] = f4 >> 3;
    wk[l] = (f4 & 7) << 2;
    wsrc[l] = W + (long)we[l] * Hdim + wk[l];
  }

  float4 xreg = make_float4(0.f, 0.f, 0.f, 0.f);
  float4 wreg[4];
  if (tid < 256) xreg = *(const float4*)(xsrc);
#pragma unroll
  for (int l = 0; l < 4; ++l) wreg[l] = *(const float4*)(wsrc[l]);

  for (int kc = 0; kc < Hdim / 32; ++kc) {
    if (tid < 256) *(float4*)&xs[xt * 36 + xk] = xreg;
#pragma unroll
    for (int l = 0; l < 4; ++l) *(float4*)&wsh[we[l] * 36 + wk[l]] = wreg[l];
    __syncthreads();
    if (kc + 1 < Hdim / 32) {
      const int ko = (kc + 1) * 32;
      if (tid < 256) xreg = *(const float4*)(xsrc + ko);
#pragma unroll
      for (int l = 0; l < 4; ++l) wreg[l] = *(const float4*)(wsrc[l] + ko);
    }
#pragma unroll
    for (int kk = 0; kk < 32; kk += 4) {
      float4 xv[4], wv[4];
#pragma unroll
      for (int i = 0; i < 4; ++i)
        xv[i] = *(const float4*)&xs[(tg * 4 + i) * 36 + kk];
#pragma unroll
      for (int j = 0; j < 4; ++j)
        wv[j] = *(const float4*)&wsh[(eg + 64 * j) * 36 + kk];
#pragma unroll
      for (int i = 0; i < 4; ++i)
#pragma unroll
        for (int j = 0; j < 4; ++j) {
          float a = acc[i][j];
          a = fmaf(xv[i].x, wv[j].x, a);
          a = fmaf(xv[i].y, wv[j].y, a);
          a = fmaf(xv[i].z, wv[j].z, a);
          a = fmaf(xv[i].w, wv[j].w, a);
          acc[i][j] = a;
        }
    }
    __syncthreads();
  }
#pragma unroll
  for (int i = 0; i < 4; ++i)
#pragma unroll
    for (int j = 0; j < 4; ++j)
      logits[(bm0 + tg * 4 + i) * (long)NE + eg + 64 * j] = acc[i][j];
}

// ---------------------------------------------------------------------------
// Phase 2: sigmoid + bias, group top2-sum, top-4 groups, masked top-8
// (descending, ties -> lower index, matching lax.top_k), normalize, scale.
// One wave (64 lanes) per token; lane l owns experts 4l..4l+3 (group = l/8).
// Outputs (float32): out[t*8+r] = idx, out[T*8 + t*8+r] = weight.
// ---------------------------------------------------------------------------
__global__ __launch_bounds__(256)
void moe_gate_topk(const float* __restrict__ logits, const float* __restrict__ bias,
                   float* __restrict__ out, int T) {
  const int tid = threadIdx.x;
  const int lane = tid & 63;
  const int wv_ = tid >> 6;
  const int t = blockIdx.x * 4 + wv_;

  const float4 lg = *(const float4*)(logits + (long)t * NE + lane * 4);
  const float4 bv = *(const float4*)(bias + lane * 4);

  const float s0 = 1.f / (1.f + expf(-lg.x));
  const float s1 = 1.f / (1.f + expf(-lg.y));
  const float s2 = 1.f / (1.f + expf(-lg.z));
  const float s3 = 1.f / (1.f + expf(-lg.w));

  const float c0 = s0 + bv.x, c1 = s1 + bv.y, c2 = s2 + bv.z, c3 = s3 + bv.w;

  // lane-local top2 of 4
  float m1 = fmaxf(c0, c1), m2 = fminf(c0, c1);
  if (c2 > m1) { m2 = m1; m1 = c2; } else m2 = fmaxf(m2, c2);
  if (c3 > m1) { m2 = m1; m1 = c3; } else m2 = fmaxf(m2, c3);
  // merge across the 8 lanes of the group (experts g*32..g*32+31)
#pragma unroll
  for (int off = 1; off < 8; off <<= 1) {
    const float o1 = __shfl_xor(m1, off);
    const float o2 = __shfl_xor(m2, off);
    if (o1 > m1) { m2 = fmaxf(m1, o2); m1 = o1; }
    else m2 = fmaxf(m2, o1);
  }
  const float gs = m1 + m2;  // group score, identical in all 8 lanes of group

  const int gme = lane >> 3;
  int rank = 0;
#pragma unroll
  for (int j = 0; j < 8; ++j) {
    const float gj = __shfl(gs, j * 8);
    rank += ((gj > gs) || (gj == gs && j < gme)) ? 1 : 0;
  }
  const bool sel = rank < 4;  // my group is in top-4 groups

  const float NEG = -INFINITY;
  float q0 = sel ? c0 : NEG, q1 = sel ? c1 : NEG;
  float q2 = sel ? c2 : NEG, q3 = sel ? c3 : NEG;

  float sum = 0.f;
  int my_e = 0;
  float my_w = 0.f;
#pragma unroll
  for (int r = 0; r < 8; ++r) {
    // lane-local argmax (strict > keeps lowest index)
    float v = q0; int ix = 0;
    if (q1 > v) { v = q1; ix = 1; }
    if (q2 > v) { v = q2; ix = 2; }
    if (q3 > v) { v = q3; ix = 3; }
    int e = lane * 4 + ix;
    // wave-wide (max value, min index) reduction
#pragma unroll
    for (int off = 1; off < 64; off <<= 1) {
      const float v2 = __shfl_xor(v, off);
      const int e2 = __shfl_xor(e, off);
      const bool take = (v2 > v) || (v2 == v && e2 < e);
      v = take ? v2 : v;
      e = take ? e2 : e;
    }
    // winner (v,e) now identical in all lanes
    const int slot = e & 3, owner = e >> 2;
    const float svs = (slot == 0) ? s0 : ((slot == 1) ? s1 : ((slot == 2) ? s2 : s3));
    const float wgt = __shfl(svs, owner);  // sigmoid score (no bias) of winner
    sum += wgt;
    if (lane == r) { my_e = e; my_w = wgt; }
    const bool own = (lane == owner);
    q0 = (own && slot == 0) ? NEG : q0;
    q1 = (own && slot == 1) ? NEG : q1;
    q2 = (own && slot == 2) ? NEG : q2;
    q3 = (own && slot == 3) ? NEG : q3;
  }

  if (lane < 8) {
    const float denom = sum + 1e-20f;
    out[(long)t * 8 + lane] = (float)my_e;
    out[(long)T * 8 + (long)t * 8 + lane] = my_w / denom * 2.5f;
  }
}

// ---------------------------------------------------------------------------
extern "C" void kernel_launch(void* const* d_in, const int* in_sizes, int n_in,
                              void* d_out, int out_size, void* d_ws, size_t ws_size,
                              hipStream_t stream) {
  const float* X = (const float*)d_in[0];   // [T, 4096]
  const float* W = (const float*)d_in[1];   // [256, 4096]
  const float* B = (const float*)d_in[2];   // [256]
  float* out = (float*)d_out;
  const int T = in_sizes[0] / Hdim;         // 16384

  float* logits = (float*)d_ws;             // needs T*256*4 = 16 MiB scratch

  moe_gate_gemm<<<T / 32, 512, 0, stream>>>(X, W, logits);
  moe_gate_topk<<<T / 4, 256, 0, stream>>>(logits, B, out, T);
}

// Round 2
// 242.526 us; speedup vs baseline: 3.6637x; 3.6637x over previous
//
#include <hip/hip_runtime.h>
#include <math.h>

#define Hdim 4096
#define NE 256
#define BM 64
#define BK 32
#define NKC (Hdim / BK)          // 128 K-chunks
#define PLANE_ELEMS (Hdim * NE)  // bf16 elements per plane (1,048,576 = 2 MB)

typedef __bf16 bf16x8 __attribute__((ext_vector_type(8)));
typedef __bf16 bf16x4 __attribute__((ext_vector_type(4)));
typedef float f32x4 __attribute__((ext_vector_type(4)));

__device__ __forceinline__ void gload_lds16(const void* g, void* l) {
  __builtin_amdgcn_global_load_lds((const __attribute__((address_space(1))) void*)g,
                                   (__attribute__((address_space(3))) void*)l, 16, 0, 0);
}

// ---------------------------------------------------------------------------
// W [256][4096] fp32 -> 3 bf16 planes (h, m, l), x = h + m + l EXACTLY.
// Plane layout: [k8 0..511][n 0..255] chunks of 8 bf16 (16 B) — i.e. element
// (n, k) lives at plane + ((k/8)*256 + n)*8 + k%8. This is the exact LDS
// image the GEMM stages with global_load_lds (16 KB contiguous per K-chunk).
// Mapping: k8 = id & 511 (coalesced reads), n = id >> 9.
// ---------------------------------------------------------------------------
__global__ __launch_bounds__(256)
void convert_w(const float* __restrict__ W, __bf16* __restrict__ pl) {
  const int id = blockIdx.x * 256 + threadIdx.x;  // 0 .. 131071
  const int k8 = id & 511;
  const int n = id >> 9;
  const float* src = W + (long)n * Hdim + k8 * 8;
  const float4 x0 = *(const float4*)src;
  const float4 x1 = *(const float4*)(src + 4);
  const float xv[8] = {x0.x, x0.y, x0.z, x0.w, x1.x, x1.y, x1.z, x1.w};
  bf16x8 vh, vm, vl;
#pragma unroll
  for (int j = 0; j < 8; ++j) {
    const float v = xv[j];
    const __bf16 h = (__bf16)v;
    const float r1 = v - (float)h;
    const __bf16 m = (__bf16)r1;
    const float r2 = r1 - (float)m;
    vh[j] = h; vm[j] = m; vl[j] = (__bf16)r2;
  }
  const long co = ((long)k8 * NE + n) * 8;
  *(bf16x8*)(pl + 0L * PLANE_ELEMS + co) = vh;
  *(bf16x8*)(pl + 1L * PLANE_ELEMS + co) = vm;
  *(bf16x8*)(pl + 2L * PLANE_ELEMS + co) = vl;
}

// ---------------------------------------------------------------------------
// Fused: logits = X @ W^T via 6-product split-bf16 MFMA, then top-k epilogue.
// Block: 512 threads (8 waves as 2M x 4N), tile BM=64 tokens x all 256 experts.
// LDS (120 KB): W bufs 2x48KB @0, X bufs 2x12KB @98304. k-sliced chunk layout
// [p][c][row] (16B = 8 k-elements) -> conflict-free b128 fragment reads.
// ---------------------------------------------------------------------------
__global__ __launch_bounds__(512, 2)
void moe_gate_fused(const float* __restrict__ X, const __bf16* __restrict__ pl,
                    const float* __restrict__ bias, float* __restrict__ out, int T) {
  __shared__ __align__(16) unsigned char smem[122880];
  const int tid = threadIdx.x;
  const int lane = tid & 63, wave = tid >> 6;
  const int wm = wave >> 2, wn = wave & 3;
  const int r16 = lane & 15, c4 = lane >> 4;
  const long bm0 = (long)blockIdx.x * BM;

  f32x4 accB[2][4], accS[2][4];
#pragma unroll
  for (int i = 0; i < 2; ++i)
#pragma unroll
    for (int j = 0; j < 4; ++j) {
      accB[i][j] = (f32x4)(0.f);
      accS[i][j] = (f32x4)(0.f);
    }

  // X staging geometry: thread -> (token xm, float4-slot xf) of the 64x32 tile
  const int xm = tid >> 3;
  const int xf = tid & 7;
  const float* xsrc = X + (bm0 + xm) * (long)Hdim + xf * 4;
  const int xws = ((xf >> 1) * 64 + xm) * 16 + (xf & 1) * 8;  // within one plane

#define STAGE_W(b, kc)                                                          \
  {                                                                             \
    _Pragma("unroll") for (int p = 0; p < 3; ++p)                               \
        _Pragma("unroll") for (int i = 0; i < 2; ++i) {                         \
      const char* g = (const char*)pl + (size_t)p * 2097152 +                   \
                      (size_t)(kc) * 16384 + (size_t)(i * 512 + tid) * 16;      \
      void* l = (void*)&smem[(b) * 49152 + p * 16384 +                          \
                             (i * 512 + (tid & ~63)) * 16];                     \
      gload_lds16(g, l);                                                        \
    }                                                                           \
  }

#define WRITE_X(b, xr)                                                          \
  {                                                                             \
    const float xa0 = (xr).x, xa1 = (xr).y, xa2 = (xr).z, xa3 = (xr).w;         \
    bf16x4 vh, vm, vl;                                                          \
    {                                                                           \
      const __bf16 h0 = (__bf16)xa0; const float r0 = xa0 - (float)h0;          \
      const __bf16 m0 = (__bf16)r0;                                             \
      vh[0] = h0; vm[0] = m0; vl[0] = (__bf16)(r0 - (float)m0);                 \
      const __bf16 h1 = (__bf16)xa1; const float r1 = xa1 - (float)h1;          \
      const __bf16 m1 = (__bf16)r1;                                             \
      vh[1] = h1; vm[1] = m1; vl[1] = (__bf16)(r1 - (float)m1);                 \
      const __bf16 h2 = (__bf16)xa2; const float r2 = xa2 - (float)h2;          \
      const __bf16 m2 = (__bf16)r2;                                             \
      vh[2] = h2; vm[2] = m2; vl[2] = (__bf16)(r2 - (float)m2);                 \
      const __bf16 h3 = (__bf16)xa3; const float r3 = xa3 - (float)h3;          \
      const __bf16 m3 = (__bf16)r3;                                             \
      vh[3] = h3; vm[3] = m3; vl[3] = (__bf16)(r3 - (float)m3);                 \
    }                                                                           \
    const int xo = 98304 + (b) * 12288;                                         \
    *(bf16x4*)&smem[xo + 0 * 4096 + xws] = vh;                                  \
    *(bf16x4*)&smem[xo + 1 * 4096 + xws] = vm;                                  \
    *(bf16x4*)&smem[xo + 2 * 4096 + xws] = vl;                                  \
  }

#define COMPUTE(b)                                                              \
  {                                                                             \
    const int wof = (b) * 49152;                                                \
    const int xo = 98304 + (b) * 12288;                                         \
    bf16x8 af[3][2], bfr[3][4];                                                 \
    _Pragma("unroll") for (int p = 0; p < 3; ++p) {                             \
      _Pragma("unroll") for (int fm = 0; fm < 2; ++fm)                          \
          af[p][fm] = *(const bf16x8*)&smem[xo + ((p * 4 + c4) * 64 +           \
                                                 (wm * 32 + fm * 16 + r16)) *   \
                                                    16];                        \
      _Pragma("unroll") for (int fn = 0; fn < 4; ++fn)                          \
          bfr[p][fn] = *(const bf16x8*)&smem[wof + ((p * 4 + c4) * 256 +        \
                                                   (wn * 64 + fn * 16 + r16)) * \
                                                      16];                      \
    }                                                                           \
    _Pragma("unroll") for (int fm = 0; fm < 2; ++fm)                            \
        _Pragma("unroll") for (int fn = 0; fn < 4; ++fn) {                      \
      accB[fm][fn] = __builtin_amdgcn_mfma_f32_16x16x32_bf16(                   \
          af[0][fm], bfr[0][fn], accB[fm][fn], 0, 0, 0);                        \
      f32x4 s = accS[fm][fn];                                                   \
      s = __builtin_amdgcn_mfma_f32_16x16x32_bf16(af[0][fm], bfr[1][fn], s, 0, 0, 0); \
      s = __builtin_amdgcn_mfma_f32_16x16x32_bf16(af[1][fm], bfr[0][fn], s, 0, 0, 0); \
      s = __builtin_amdgcn_mfma_f32_16x16x32_bf16(af[0][fm], bfr[2][fn], s, 0, 0, 0); \
      s = __builtin_amdgcn_mfma_f32_16x16x32_bf16(af[2][fm], bfr[0][fn], s, 0, 0, 0); \
      s = __builtin_amdgcn_mfma_f32_16x16x32_bf16(af[1][fm], bfr[1][fn], s, 0, 0, 0); \
      accS[fm][fn] = s;                                                         \
    }                                                                           \
  }

  // prologue
  STAGE_W(0, 0);
  {
    const float4 x0 = *(const float4*)(xsrc);
    WRITE_X(0, x0);
  }
  __syncthreads();

  for (int kc = 0; kc < NKC; ++kc) {
    const int cb = kc & 1;
    float4 xn;
    const bool more = (kc + 1 < NKC);
    if (more) {
      STAGE_W(cb ^ 1, kc + 1);
      xn = *(const float4*)(xsrc + (size_t)(kc + 1) * BK);  // issue early (T14)
    }
    COMPUTE(cb);
    if (more) WRITE_X(cb ^ 1, xn);  // write late, after compute
    __syncthreads();
  }

  // ---- epilogue: logits -> LDS [64][260] fp32, then fused top-k ----
  float* lg = (float*)smem;
#pragma unroll
  for (int fm = 0; fm < 2; ++fm)
#pragma unroll
    for (int fn = 0; fn < 4; ++fn)
#pragma unroll
      for (int r = 0; r < 4; ++r) {
        const int t = wm * 32 + fm * 16 + c4 * 4 + r;
        const int n = wn * 64 + fn * 16 + r16;
        lg[t * 260 + n] = accB[fm][fn][r] + accS[fm][fn][r];
      }
  __syncthreads();

  // phase 2 (verified round-1 logic): wave processes 8 tokens sequentially
  const float4 bv = *(const float4*)(bias + lane * 4);
  for (int i = 0; i < 8; ++i) {
    const int t = wave * 8 + i;
    const float4 lgv = *(const float4*)&lg[t * 260 + lane * 4];

    const float s0 = 1.f / (1.f + expf(-lgv.x));
    const float s1 = 1.f / (1.f + expf(-lgv.y));
    const float s2 = 1.f / (1.f + expf(-lgv.z));
    const float s3 = 1.f / (1.f + expf(-lgv.w));

    const float c0 = s0 + bv.x, c1 = s1 + bv.y, c2 = s2 + bv.z, c3 = s3 + bv.w;

    // lane-local top2 of 4
    float m1 = fmaxf(c0, c1), m2 = fminf(c0, c1);
    if (c2 > m1) { m2 = m1; m1 = c2; } else m2 = fmaxf(m2, c2);
    if (c3 > m1) { m2 = m1; m1 = c3; } else m2 = fmaxf(m2, c3);
#pragma unroll
    for (int off = 1; off < 8; off <<= 1) {
      const float o1 = __shfl_xor(m1, off);
      const float o2 = __shfl_xor(m2, off);
      if (o1 > m1) { m2 = fmaxf(m1, o2); m1 = o1; }
      else m2 = fmaxf(m2, o1);
    }
    const float gs = m1 + m2;  // group score (identical across the 8 lanes)

    const int gme = lane >> 3;
    int rank = 0;
#pragma unroll
    for (int j = 0; j < 8; ++j) {
      const float gj = __shfl(gs, j * 8);
      rank += ((gj > gs) || (gj == gs && j < gme)) ? 1 : 0;
    }
    const bool sel = rank < 4;

    const float NEG = -INFINITY;
    float q0 = sel ? c0 : NEG, q1 = sel ? c1 : NEG;
    float q2 = sel ? c2 : NEG, q3 = sel ? c3 : NEG;

    float sum = 0.f;
    int my_e = 0;
    float my_w = 0.f;
#pragma unroll
    for (int r = 0; r < 8; ++r) {
      float v = q0; int ix = 0;
      if (q1 > v) { v = q1; ix = 1; }
      if (q2 > v) { v = q2; ix = 2; }
      if (q3 > v) { v = q3; ix = 3; }
      int e = lane * 4 + ix;
#pragma unroll
      for (int off = 1; off < 64; off <<= 1) {
        const float v2 = __shfl_xor(v, off);
        const int e2 = __shfl_xor(e, off);
        const bool take = (v2 > v) || (v2 == v && e2 < e);
        v = take ? v2 : v;
        e = take ? e2 : e;
      }
      const int slot = e & 3, owner = e >> 2;
      const float svs = (slot == 0) ? s0 : ((slot == 1) ? s1 : ((slot == 2) ? s2 : s3));
      const float wgt = __shfl(svs, owner);
      sum += wgt;
      if (lane == r) { my_e = e; my_w = wgt; }
      const bool own = (lane == owner);
      q0 = (own && slot == 0) ? NEG : q0;
      q1 = (own && slot == 1) ? NEG : q1;
      q2 = (own && slot == 2) ? NEG : q2;
      q3 = (own && slot == 3) ? NEG : q3;
    }

    if (lane < 8) {
      const float denom = sum + 1e-20f;
      const long tg = bm0 + t;
      out[tg * 8 + lane] = (float)my_e;
      out[(long)T * 8 + tg * 8 + lane] = my_w / denom * 2.5f;
    }
  }
}

// ---------------------------------------------------------------------------
extern "C" void kernel_launch(void* const* d_in, const int* in_sizes, int n_in,
                              void* d_out, int out_size, void* d_ws, size_t ws_size,
                              hipStream_t stream) {
  const float* X = (const float*)d_in[0];   // [T, 4096]
  const float* W = (const float*)d_in[1];   // [256, 4096]
  const float* B = (const float*)d_in[2];   // [256]
  float* out = (float*)d_out;
  const int T = in_sizes[0] / Hdim;         // 16384

  __bf16* planes = (__bf16*)d_ws;           // 3 x 2 MB = 6 MB scratch

  convert_w<<<512, 256, 0, stream>>>(W, planes);
  moe_gate_fused<<<T / BM, 512, 0, stream>>>(X, planes, B, out, T);
}

// Round 3
// 195.145 us; speedup vs baseline: 4.5533x; 1.2428x over previous
//
#include <hip/hip_runtime.h>
#include <math.h>

#define Hdim 4096
#define NE 256
#define BM 64
#define BK 32
#define NKC (Hdim / BK)          // 128 K-chunks
#define PLANE_ELEMS (Hdim * NE)  // f16 elements per plane (1,048,576 = 2 MB)
#define PLANE_BYTES (PLANE_ELEMS * 2)

// Scales (exact powers of two; undone in epilogue):
//   W' = 64*w, X' = 16*x, m-planes additionally *2048.
//   logit = (acc0 + acc1*2^-11 + acc2*2^-22) * 2^-10
#define C0 9.765625e-4f            // 2^-10
#define C1 4.76837158203125e-7f    // 2^-21
#define C2 2.3283064365386963e-10f // 2^-32

typedef _Float16 f16x8 __attribute__((ext_vector_type(8)));
typedef _Float16 f16x4 __attribute__((ext_vector_type(4)));
typedef float f32x4 __attribute__((ext_vector_type(4)));

__device__ __forceinline__ void gload_lds16(const void* g, void* l) {
  __builtin_amdgcn_global_load_lds((const __attribute__((address_space(1))) void*)g,
                                   (__attribute__((address_space(3))) void*)l, 16, 0, 0);
}

// ---------------------------------------------------------------------------
// W [256][4096] fp32 -> 2 f16 planes: h = f16(64w), m = f16((64w - h)*2048).
// Plane layout: [k8 0..511][n 0..255] chunks of 8 f16 (16 B): element (n,k)
// at plane + ((k/8)*256 + n)*8 + k%8 — the exact LDS image staged per chunk.
// ---------------------------------------------------------------------------
__global__ __launch_bounds__(256)
void convert_w(const float* __restrict__ W, _Float16* __restrict__ pl) {
  const int id = blockIdx.x * 256 + threadIdx.x;  // 0 .. 131071
  const int k8 = id & 511;
  const int n = id >> 9;
  const float* src = W + (long)n * Hdim + k8 * 8;
  const float4 x0 = *(const float4*)src;
  const float4 x1 = *(const float4*)(src + 4);
  const float xv[8] = {x0.x, x0.y, x0.z, x0.w, x1.x, x1.y, x1.z, x1.w};
  f16x8 vh, vm;
#pragma unroll
  for (int j = 0; j < 8; ++j) {
    const float v = xv[j] * 64.f;
    const _Float16 h = (_Float16)v;
    const float r = (v - (float)h) * 2048.f;
    vh[j] = h;
    vm[j] = (_Float16)r;
  }
  const long co = ((long)k8 * NE + n) * 8;
  *(f16x8*)(pl + co) = vh;
  *(f16x8*)(pl + PLANE_ELEMS + co) = vm;
}

// ---------------------------------------------------------------------------
// Fused: logits = X @ W^T via 4-product split-f16 MFMA, then top-k epilogue.
// Block: 512 threads (8 waves as 2M x 4N), tile BM=64 tokens x all 256 experts.
// LDS 80 KB: W bufs 2x32KB @0, X bufs 2x8KB @65536. k-sliced 16B-chunk layout
// -> conflict-light b128 fragment reads, linear global_load_lds staging.
// ---------------------------------------------------------------------------
__global__ __launch_bounds__(512, 2)
void moe_gate_fused(const float* __restrict__ X, const _Float16* __restrict__ pl,
                    const float* __restrict__ bias, float* __restrict__ out, int T) {
  __shared__ __align__(16) unsigned char smem[81920];
  const int tid = threadIdx.x;
  const int lane = tid & 63, wave = tid >> 6;
  const int wm = wave >> 2, wn = wave & 3;
  const int r16 = lane & 15, c4 = lane >> 4;
  const long bm0 = (long)blockIdx.x * BM;

  f32x4 acc0[2][4], acc1[2][4], acc2[2][4];
#pragma unroll
  for (int i = 0; i < 2; ++i)
#pragma unroll
    for (int j = 0; j < 4; ++j) {
      acc0[i][j] = (f32x4)(0.f);
      acc1[i][j] = (f32x4)(0.f);
      acc2[i][j] = (f32x4)(0.f);
    }

  // X staging geometry: thread -> (token xm, float4-slot xf) of the 64x32 tile
  const int xm = tid >> 3;
  const int xf = tid & 7;
  const float* xsrc = X + (bm0 + xm) * (long)Hdim + xf * 4;
  const int xws = ((xf >> 1) * 64 + xm) * 16 + (xf & 1) * 8;  // within one plane

#define STAGE_W(b, kc)                                                          \
  {                                                                             \
    _Pragma("unroll") for (int p = 0; p < 2; ++p)                               \
        _Pragma("unroll") for (int i = 0; i < 2; ++i) {                         \
      const char* g = (const char*)pl + (size_t)p * PLANE_BYTES +               \
                      (size_t)(kc) * 16384 + (size_t)(i * 512 + tid) * 16;      \
      void* l = (void*)&smem[(b) * 32768 + p * 16384 +                          \
                             (i * 512 + (tid & ~63)) * 16];                     \
      gload_lds16(g, l);                                                        \
    }                                                                           \
  }

#define WRITE_X(b, xr)                                                          \
  {                                                                             \
    f16x4 vh, vm;                                                               \
    const float xa[4] = {(xr).x, (xr).y, (xr).z, (xr).w};                       \
    _Pragma("unroll") for (int j = 0; j < 4; ++j) {                             \
      const float v = xa[j] * 16.f;                                             \
      const _Float16 h = (_Float16)v;                                           \
      const float r = (v - (float)h) * 2048.f;                                  \
      vh[j] = h;                                                                \
      vm[j] = (_Float16)r;                                                      \
    }                                                                           \
    const int xo = 65536 + (b) * 8192;                                          \
    *(f16x4*)&smem[xo + 0 * 4096 + xws] = vh;                                   \
    *(f16x4*)&smem[xo + 1 * 4096 + xws] = vm;                                   \
  }

#define COMPUTE(b)                                                              \
  {                                                                             \
    const int wof = (b) * 32768;                                                \
    const int xo = 65536 + (b) * 8192;                                          \
    f16x8 af[2][2], bfr[2][4];                                                  \
    _Pragma("unroll") for (int p = 0; p < 2; ++p) {                             \
      _Pragma("unroll") for (int fm = 0; fm < 2; ++fm)                          \
          af[p][fm] = *(const f16x8*)&smem[xo + p * 4096 +                      \
                                           (c4 * 64 +                           \
                                            (wm * 32 + fm * 16 + r16)) * 16];   \
      _Pragma("unroll") for (int fn = 0; fn < 4; ++fn)                          \
          bfr[p][fn] = *(const f16x8*)&smem[wof + p * 16384 +                   \
                                            (c4 * 256 +                         \
                                             (wn * 64 + fn * 16 + r16)) * 16];  \
    }                                                                           \
    _Pragma("unroll") for (int fm = 0; fm < 2; ++fm)                            \
        _Pragma("unroll") for (int fn = 0; fn < 4; ++fn) {                      \
      acc0[fm][fn] = __builtin_amdgcn_mfma_f32_16x16x32_f16(                    \
          af[0][fm], bfr[0][fn], acc0[fm][fn], 0, 0, 0);                        \
      f32x4 s = acc1[fm][fn];                                                   \
      s = __builtin_amdgcn_mfma_f32_16x16x32_f16(af[0][fm], bfr[1][fn], s, 0, 0, 0); \
      s = __builtin_amdgcn_mfma_f32_16x16x32_f16(af[1][fm], bfr[0][fn], s, 0, 0, 0); \
      acc1[fm][fn] = s;                                                         \
      acc2[fm][fn] = __builtin_amdgcn_mfma_f32_16x16x32_f16(                    \
          af[1][fm], bfr[1][fn], acc2[fm][fn], 0, 0, 0);                        \
    }                                                                           \
  }

  // prologue
  STAGE_W(0, 0);
  {
    const float4 x0 = *(const float4*)(xsrc);
    WRITE_X(0, x0);
  }
  __syncthreads();

  for (int kc = 0; kc < NKC; ++kc) {
    const int cb = kc & 1;
    float4 xn;
    const bool more = (kc + 1 < NKC);
    if (more) {
      STAGE_W(cb ^ 1, kc + 1);
      xn = *(const float4*)(xsrc + (size_t)(kc + 1) * BK);  // issue early (T14)
    }
    COMPUTE(cb);
    if (more) WRITE_X(cb ^ 1, xn);  // write late, after compute
    __syncthreads();
  }

  // ---- epilogue: logits -> LDS [64][260] fp32, then fused top-k ----
  float* lg = (float*)smem;
#pragma unroll
  for (int fm = 0; fm < 2; ++fm)
#pragma unroll
    for (int fn = 0; fn < 4; ++fn)
#pragma unroll
      for (int r = 0; r < 4; ++r) {
        const int t = wm * 32 + fm * 16 + c4 * 4 + r;
        const int n = wn * 64 + fn * 16 + r16;
        lg[t * 260 + n] =
            fmaf(acc2[fm][fn][r], C2,
                 fmaf(acc1[fm][fn][r], C1, acc0[fm][fn][r] * C0));
      }
  __syncthreads();

  // phase 2 (verified round-1/2 logic): wave processes 8 tokens sequentially
  const float4 bv = *(const float4*)(bias + lane * 4);
  for (int i = 0; i < 8; ++i) {
    const int t = wave * 8 + i;
    const float4 lgv = *(const float4*)&lg[t * 260 + lane * 4];

    const float s0 = 1.f / (1.f + expf(-lgv.x));
    const float s1 = 1.f / (1.f + expf(-lgv.y));
    const float s2 = 1.f / (1.f + expf(-lgv.z));
    const float s3 = 1.f / (1.f + expf(-lgv.w));

    const float c0 = s0 + bv.x, c1 = s1 + bv.y, c2 = s2 + bv.z, c3 = s3 + bv.w;

    // lane-local top2 of 4
    float m1 = fmaxf(c0, c1), m2 = fminf(c0, c1);
    if (c2 > m1) { m2 = m1; m1 = c2; } else m2 = fmaxf(m2, c2);
    if (c3 > m1) { m2 = m1; m1 = c3; } else m2 = fmaxf(m2, c3);
#pragma unroll
    for (int off = 1; off < 8; off <<= 1) {
      const float o1 = __shfl_xor(m1, off);
      const float o2 = __shfl_xor(m2, off);
      if (o1 > m1) { m2 = fmaxf(m1, o2); m1 = o1; }
      else m2 = fmaxf(m2, o1);
    }
    const float gs = m1 + m2;  // group score (identical across the 8 lanes)

    const int gme = lane >> 3;
    int rank = 0;
#pragma unroll
    for (int j = 0; j < 8; ++j) {
      const float gj = __shfl(gs, j * 8);
      rank += ((gj > gs) || (gj == gs && j < gme)) ? 1 : 0;
    }
    const bool sel = rank < 4;

    const float NEG = -INFINITY;
    float q0 = sel ? c0 : NEG, q1 = sel ? c1 : NEG;
    float q2 = sel ? c2 : NEG, q3 = sel ? c3 : NEG;

    float sum = 0.f;
    int my_e = 0;
    float my_w = 0.f;
#pragma unroll
    for (int r = 0; r < 8; ++r) {
      float v = q0; int ix = 0;
      if (q1 > v) { v = q1; ix = 1; }
      if (q2 > v) { v = q2; ix = 2; }
      if (q3 > v) { v = q3; ix = 3; }
      int e = lane * 4 + ix;
#pragma unroll
      for (int off = 1; off < 64; off <<= 1) {
        const float v2 = __shfl_xor(v, off);
        const int e2 = __shfl_xor(e, off);
        const bool take = (v2 > v) || (v2 == v && e2 < e);
        v = take ? v2 : v;
        e = take ? e2 : e;
      }
      const int slot = e & 3, owner = e >> 2;
      const float svs = (slot == 0) ? s0 : ((slot == 1) ? s1 : ((slot == 2) ? s2 : s3));
      const float wgt = __shfl(svs, owner);
      sum += wgt;
      if (lane == r) { my_e = e; my_w = wgt; }
      const bool own = (lane == owner);
      q0 = (own && slot == 0) ? NEG : q0;
      q1 = (own && slot == 1) ? NEG : q1;
      q2 = (own && slot == 2) ? NEG : q2;
      q3 = (own && slot == 3) ? NEG : q3;
    }

    if (lane < 8) {
      const float denom = sum + 1e-20f;
      const long tg = bm0 + t;
      out[tg * 8 + lane] = (float)my_e;
      out[(long)T * 8 + tg * 8 + lane] = my_w / denom * 2.5f;
    }
  }
}

// ---------------------------------------------------------------------------
extern "C" void kernel_launch(void* const* d_in, const int* in_sizes, int n_in,
                              void* d_out, int out_size, void* d_ws, size_t ws_size,
                              hipStream_t stream) {
  const float* X = (const float*)d_in[0];   // [T, 4096]
  const float* W = (const float*)d_in[1];   // [256, 4096]
  const float* B = (const float*)d_in[2];   // [256]
  float* out = (float*)d_out;
  const int T = in_sizes[0] / Hdim;         // 16384

  _Float16* planes = (_Float16*)d_ws;       // 2 x 2 MB = 4 MB scratch

  convert_w<<<512, 256, 0, stream>>>(W, planes);
  moe_gate_fused<<<T / BM, 512, 0, stream>>>(X, planes, B, out, T);
}